// Round 3
// baseline (274.036 us; speedup 1.0000x reference)
//
#include <hip/hip_runtime.h>
#include <math.h>

// Problem constants (fixed by setup_inputs in the reference)
constexpr int B_ = 2, C_ = 64, H_ = 180, W_ = 360;
constexpr int HW = H_ * W_;            // 64800
constexpr int Hp = H_ + 2, Wp = W_ + 2; // padded dims 182 x 362
constexpr int CGROUPS = 2;             // channel groups (blocks) per pixel tile
constexpr int CPT = C_ / CGROUPS;      // channels per thread = 32
constexpr int PXT = 256;               // pixels per block
constexpr int TILES = (HW + PXT - 1) / PXT; // 254

__device__ __forceinline__ float frem(float x, float y) {
    // jnp.remainder for y > 0
    return x - floorf(x / y) * y;
}

// bicubic weights, A = -0.75
__device__ __forceinline__ float cub1(float x) {   // for |t| <= 1 distances
    return (1.25f * x - 2.25f) * x * x + 1.0f;
}
__device__ __forceinline__ float cub2(float x) {   // for 1 < |t| < 2 distances
    return ((-0.75f * x + 3.75f) * x - 6.0f) * x + 3.0f;
}

// Read geo_cyclic_pad(hidden,1)[y][x] directly from the unpadded image.
// y in [0,Hp-1], x in [0,Wp-1]. Columns wrap; top/bottom rows are the first/
// last original row rolled by W/2 in longitude (flip of a 1-row slice is id).
__device__ __forceinline__ float fetch_pad(const float* __restrict__ img, int y, int x) {
    int wc = x - 1;
    if (x == 0)      wc = W_ - 1;
    if (x == Wp - 1) wc = 0;
    int hh = y - 1;
    bool top = (y == 0), bot = (y == Hp - 1);
    if (top) hh = 0;
    if (bot) hh = H_ - 1;
    if (top || bot) { wc += W_ / 2; if (wc >= W_) wc -= W_; }
    return img[hh * W_ + wc];
}

__global__ __launch_bounds__(PXT) void nsl_fused(
    const float* __restrict__ hidden,    // (B,C,H,W)
    const float* __restrict__ lat_grid,  // (B,H,W)
    const float* __restrict__ lon_grid,  // (B,H,W)
    const float* __restrict__ W_vel,     // (2C, C) row-major
    const float* __restrict__ b_vel,     // (2C)
    const float* __restrict__ dt_p,      // scalar
    float* __restrict__ out)             // (B,C,H,W)
{
    const int bid  = blockIdx.x;
    const int tile = bid % TILES;
    const int cg   = (bid / TILES) % CGROUPS;
    const int b    = bid / (TILES * CGROUPS);
    const int px   = tile * PXT + threadIdx.x;
    if (px >= HW) return;

    const float dt      = dt_p[0];
    const float min_lat = lat_grid[0];
    const float max_lat = lat_grid[(H_ - 1) * W_];   // lat monotone in h
    const float min_lon = lon_grid[0];
    const float max_lon = lon_grid[W_ - 1];          // lon monotone in w
    const float two_pi  = 6.2831853071795864769f;

    const float lat_p = lat_grid[(size_t)b * HW + px];
    const float lon_p = lon_grid[(size_t)b * HW + px];
    float sp, cp;
    __sincosf(lat_p, &sp, &cp);

    // Load this pixel's 64-channel column into registers (coalesced per k).
    float xcol[C_];
    const float* hb = hidden + (size_t)b * C_ * HW + px;
#pragma unroll
    for (int k = 0; k < C_; ++k) xcol[k] = hb[k * HW];

    const float inv_dlat = 2.0f / (max_lat - min_lat);
    const float inv_dlon = 2.0f / (max_lon - min_lon);
    const float sxw = (float)W_ / (float)Wp;
    const float syh = (float)H_ / (float)Hp;

    for (int i = 0; i < CPT; ++i) {
        const int c = cg * CPT + i;                 // block-uniform channel
        const float* __restrict__ wu = W_vel + (size_t)c * C_;
        const float* __restrict__ wv = W_vel + (size_t)(C_ + c) * C_;
        float u = b_vel[c];
        float v = b_vel[C_ + c];
#pragma unroll
        for (int k = 0; k < C_; ++k) {
            u = fmaf(wu[k], xcol[k], u);            // scalar W operand
            v = fmaf(wv[k], xcol[k], v);
        }

        // departure point on the sphere
        const float lon_pr = -u * dt;
        const float lat_pr = -v * dt;
        float slp, clp, slo, clo;
        __sincosf(lat_pr, &slp, &clp);
        __sincosf(lon_pr, &slo, &clo);
        float sin_lat = slp * cp + clp * clo * sp;
        sin_lat = fminf(fmaxf(sin_lat, -1.0f + 1e-7f), 1.0f - 1e-7f);
        const float lat = asinf(sin_lat);
        const float num = clp * slo;
        const float den = clp * clo * cp - slp * sp;
        const float lon = frem(lon_p + atan2f(num, den) + two_pi, two_pi);

        // normalized grid coords with cyclic/pole wrapping
        float gx = (lon - min_lon) * inv_dlon - 1.0f;
        float gy = (lat - min_lat) * inv_dlat - 1.0f;
        gx = frem(gx + 1.0f, 2.0f) - 1.0f;
        const bool left  = (gx <= 0.0f);
        const bool outer = (fabsf(gy) > 1.0f);
        if (outer) gx += left ? 1.0f : -1.0f;
        if (gy < -1.0f)     gy = -(2.0f + gy);
        else if (gy > 1.0f) gy = 2.0f - gy;
        gx *= sxw;
        gy *= syh;

        // bicubic sample of the (virtually) padded image
        const float ix = (gx + 1.0f) * 0.5f * (float)(Wp - 1);
        const float iy = (gy + 1.0f) * 0.5f * (float)(Hp - 1);
        const float fx0 = floorf(ix), fy0 = floorf(iy);
        const float tx = ix - fx0, ty = iy - fy0;
        const int jx = (int)fx0, jy = (int)fy0;

        const float wx0 = cub2(tx + 1.0f), wx1 = cub1(tx);
        const float wx2 = cub1(1.0f - tx), wx3 = cub2(2.0f - tx);
        const float wy0 = cub2(ty + 1.0f), wy1 = cub1(ty);
        const float wy2 = cub1(1.0f - ty), wy3 = cub2(2.0f - ty);

        const float* __restrict__ img = hidden + ((size_t)b * C_ + c) * HW;
        const int xs0 = min(max(jx - 1, 0), Wp - 1);
        const int xs1 = min(max(jx,     0), Wp - 1);
        const int xs2 = min(max(jx + 1, 0), Wp - 1);
        const int xs3 = min(max(jx + 2, 0), Wp - 1);
        const int ys0 = min(max(jy - 1, 0), Hp - 1);
        const int ys1 = min(max(jy,     0), Hp - 1);
        const int ys2 = min(max(jy + 1, 0), Hp - 1);
        const int ys3 = min(max(jy + 2, 0), Hp - 1);

        float r0 = wx0 * fetch_pad(img, ys0, xs0) + wx1 * fetch_pad(img, ys0, xs1)
                 + wx2 * fetch_pad(img, ys0, xs2) + wx3 * fetch_pad(img, ys0, xs3);
        float r1 = wx0 * fetch_pad(img, ys1, xs0) + wx1 * fetch_pad(img, ys1, xs1)
                 + wx2 * fetch_pad(img, ys1, xs2) + wx3 * fetch_pad(img, ys1, xs3);
        float r2 = wx0 * fetch_pad(img, ys2, xs0) + wx1 * fetch_pad(img, ys2, xs1)
                 + wx2 * fetch_pad(img, ys2, xs2) + wx3 * fetch_pad(img, ys2, xs3);
        float r3 = wx0 * fetch_pad(img, ys3, xs0) + wx1 * fetch_pad(img, ys3, xs1)
                 + wx2 * fetch_pad(img, ys3, xs2) + wx3 * fetch_pad(img, ys3, xs3);

        out[((size_t)b * C_ + c) * HW + px] = wy0 * r0 + wy1 * r1 + wy2 * r2 + wy3 * r3;
    }
}

extern "C" void kernel_launch(void* const* d_in, const int* in_sizes, int n_in,
                              void* d_out, int out_size, void* d_ws, size_t ws_size,
                              hipStream_t stream) {
    const float* hidden   = (const float*)d_in[0];
    const float* lat_grid = (const float*)d_in[1];
    const float* lon_grid = (const float*)d_in[2];
    const float* W_vel    = (const float*)d_in[3];
    const float* b_vel    = (const float*)d_in[4];
    const float* dt_p     = (const float*)d_in[5];
    float* out = (float*)d_out;

    const int grid = B_ * CGROUPS * TILES; // 1016 blocks
    nsl_fused<<<grid, PXT, 0, stream>>>(hidden, lat_grid, lon_grid, W_vel, b_vel, dt_p, out);
}

// Round 4
// 273.008 us; speedup vs baseline: 1.0038x; 1.0038x over previous
//
#include <hip/hip_runtime.h>
#include <math.h>

// Problem constants (fixed by setup_inputs in the reference)
constexpr int B_ = 2, C_ = 64, H_ = 180, W_ = 360;
constexpr int HW = H_ * W_;             // 64800
constexpr int Hp = H_ + 2, Wp = W_ + 2; // padded dims 182 x 362
constexpr int CGROUPS = 4;              // channel groups (blocks) per pixel tile
constexpr int CPT = C_ / CGROUPS;       // channels per block = 16
constexpr int PXT = 64;                 // pixels per block (one wave)
constexpr int TILES = (HW + PXT - 1) / PXT; // 1013

__device__ __forceinline__ float frem(float x, float y) {
    // jnp.remainder for y > 0
    return x - floorf(x / y) * y;
}

// bicubic weights, A = -0.75
__device__ __forceinline__ float cub1(float x) {   // for |t| <= 1 distances
    return (1.25f * x - 2.25f) * x * x + 1.0f;
}
__device__ __forceinline__ float cub2(float x) {   // for 1 < |t| < 2 distances
    return ((-0.75f * x + 3.75f) * x - 6.0f) * x + 3.0f;
}

// Read geo_cyclic_pad(hidden,1)[y][x] directly from the unpadded image.
// y in [0,Hp-1], x in [0,Wp-1]. Columns wrap; top/bottom rows are the first/
// last original row rolled by W/2 in longitude (flip of a 1-row slice is id).
__device__ __forceinline__ float fetch_pad(const float* __restrict__ img, int y, int x) {
    int wc = x - 1;
    if (x == 0)      wc = W_ - 1;
    if (x == Wp - 1) wc = 0;
    int hh = y - 1;
    bool top = (y == 0), bot = (y == Hp - 1);
    if (top) hh = 0;
    if (bot) hh = H_ - 1;
    if (top || bot) { wc += W_ / 2; if (wc >= W_) wc -= W_; }
    return img[hh * W_ + wc];
}

__global__ __launch_bounds__(PXT) void nsl_fused(
    const float* __restrict__ hidden,    // (B,C,H,W)
    const float* __restrict__ lat_grid,  // (B,H,W)
    const float* __restrict__ lon_grid,  // (B,H,W)
    const float* __restrict__ W_vel,     // (2C, C) row-major
    const float* __restrict__ b_vel,     // (2C)
    const float* __restrict__ dt_p,      // scalar
    float* __restrict__ out)             // (B,C,H,W)
{
    const int bid  = blockIdx.x;
    const int tile = bid % TILES;
    const int cg   = (bid / TILES) % CGROUPS;
    const int b    = bid / (TILES * CGROUPS);
    const int px   = tile * PXT + threadIdx.x;
    if (px >= HW) return;

    const float dt      = dt_p[0];
    const float min_lat = lat_grid[0];
    const float max_lat = lat_grid[(H_ - 1) * W_];   // lat monotone in h
    const float min_lon = lon_grid[0];
    const float max_lon = lon_grid[W_ - 1];          // lon monotone in w
    const float two_pi  = 6.2831853071795864769f;

    const float lat_p = lat_grid[(size_t)b * HW + px];
    const float lon_p = lon_grid[(size_t)b * HW + px];
    float sp, cp;
    __sincosf(lat_p, &sp, &cp);

    // ---- Phase 1: k-streaming 1x1-conv GEMM ----
    // CPT (u,v) accumulator pairs stay in VGPRs; each input channel k is
    // loaded ONCE (coalesced) and applied to all CPT outputs with
    // block-uniform W_vel operands (scalar pipe).
    float u[CPT], v[CPT];
#pragma unroll
    for (int i = 0; i < CPT; ++i) {
        u[i] = b_vel[cg * CPT + i];
        v[i] = b_vel[C_ + cg * CPT + i];
    }
    const float* hb = hidden + (size_t)b * C_ * HW + px;
#pragma unroll 2
    for (int k = 0; k < C_; ++k) {
        const float x = hb[(size_t)k * HW];
#pragma unroll
        for (int i = 0; i < CPT; ++i) {
            u[i] = fmaf(W_vel[(size_t)(cg * CPT + i) * C_ + k], x, u[i]);
            v[i] = fmaf(W_vel[(size_t)(C_ + cg * CPT + i) * C_ + k], x, v[i]);
        }
    }

    const float inv_dlat = 2.0f / (max_lat - min_lat);
    const float inv_dlon = 2.0f / (max_lon - min_lon);
    const float sxw = (float)W_ / (float)Wp;
    const float syh = (float)H_ / (float)Hp;

    // ---- Phase 2: per-channel departure point + bicubic gather ----
    for (int i = 0; i < CPT; ++i) {
        const int c = cg * CPT + i;                 // block-uniform channel

        // departure point on the sphere
        const float lon_pr = -u[i] * dt;
        const float lat_pr = -v[i] * dt;
        float slp, clp, slo, clo;
        __sincosf(lat_pr, &slp, &clp);
        __sincosf(lon_pr, &slo, &clo);
        float sin_lat = slp * cp + clp * clo * sp;
        sin_lat = fminf(fmaxf(sin_lat, -1.0f + 1e-7f), 1.0f - 1e-7f);
        const float lat = asinf(sin_lat);
        const float num = clp * slo;
        const float den = clp * clo * cp - slp * sp;
        const float lon = frem(lon_p + atan2f(num, den) + two_pi, two_pi);

        // normalized grid coords with cyclic/pole wrapping
        float gx = (lon - min_lon) * inv_dlon - 1.0f;
        float gy = (lat - min_lat) * inv_dlat - 1.0f;
        gx = frem(gx + 1.0f, 2.0f) - 1.0f;
        const bool left  = (gx <= 0.0f);
        const bool outer = (fabsf(gy) > 1.0f);
        if (outer) gx += left ? 1.0f : -1.0f;
        if (gy < -1.0f)     gy = -(2.0f + gy);
        else if (gy > 1.0f) gy = 2.0f - gy;
        gx *= sxw;
        gy *= syh;

        // bicubic sample of the (virtually) padded image
        const float ix = (gx + 1.0f) * 0.5f * (float)(Wp - 1);
        const float iy = (gy + 1.0f) * 0.5f * (float)(Hp - 1);
        const float fx0 = floorf(ix), fy0 = floorf(iy);
        const float tx = ix - fx0, ty = iy - fy0;
        const int jx = (int)fx0, jy = (int)fy0;

        const float wx0 = cub2(tx + 1.0f), wx1 = cub1(tx);
        const float wx2 = cub1(1.0f - tx), wx3 = cub2(2.0f - tx);
        const float wy0 = cub2(ty + 1.0f), wy1 = cub1(ty);
        const float wy2 = cub1(1.0f - ty), wy3 = cub2(2.0f - ty);

        const float* __restrict__ img = hidden + ((size_t)b * C_ + c) * HW;
        const int xs0 = min(max(jx - 1, 0), Wp - 1);
        const int xs1 = min(max(jx,     0), Wp - 1);
        const int xs2 = min(max(jx + 1, 0), Wp - 1);
        const int xs3 = min(max(jx + 2, 0), Wp - 1);
        const int ys0 = min(max(jy - 1, 0), Hp - 1);
        const int ys1 = min(max(jy,     0), Hp - 1);
        const int ys2 = min(max(jy + 1, 0), Hp - 1);
        const int ys3 = min(max(jy + 2, 0), Hp - 1);

        float r0 = wx0 * fetch_pad(img, ys0, xs0) + wx1 * fetch_pad(img, ys0, xs1)
                 + wx2 * fetch_pad(img, ys0, xs2) + wx3 * fetch_pad(img, ys0, xs3);
        float r1 = wx0 * fetch_pad(img, ys1, xs0) + wx1 * fetch_pad(img, ys1, xs1)
                 + wx2 * fetch_pad(img, ys1, xs2) + wx3 * fetch_pad(img, ys1, xs3);
        float r2 = wx0 * fetch_pad(img, ys2, xs0) + wx1 * fetch_pad(img, ys2, xs1)
                 + wx2 * fetch_pad(img, ys2, xs2) + wx3 * fetch_pad(img, ys2, xs3);
        float r3 = wx0 * fetch_pad(img, ys3, xs0) + wx1 * fetch_pad(img, ys3, xs1)
                 + wx2 * fetch_pad(img, ys3, xs2) + wx3 * fetch_pad(img, ys3, xs3);

        out[((size_t)b * C_ + c) * HW + px] = wy0 * r0 + wy1 * r1 + wy2 * r2 + wy3 * r3;
    }
}

extern "C" void kernel_launch(void* const* d_in, const int* in_sizes, int n_in,
                              void* d_out, int out_size, void* d_ws, size_t ws_size,
                              hipStream_t stream) {
    const float* hidden   = (const float*)d_in[0];
    const float* lat_grid = (const float*)d_in[1];
    const float* lon_grid = (const float*)d_in[2];
    const float* W_vel    = (const float*)d_in[3];
    const float* b_vel    = (const float*)d_in[4];
    const float* dt_p     = (const float*)d_in[5];
    float* out = (float*)d_out;

    const int grid = B_ * CGROUPS * TILES; // 8104 wave-sized blocks
    nsl_fused<<<grid, PXT, 0, stream>>>(hidden, lat_grid, lon_grid, W_vel, b_vel, dt_p, out);
}